// Round 1
// 157.628 us; speedup vs baseline: 1.0372x; 1.0372x over previous
//
#include <hip/hip_runtime.h>
#include <math.h>

#define NFFT  1024
#define TIME_ 262144
#define NWIN  1021   // (262144 - 1024)/256 + 1
#define NPAIR 511    // pair p covers windows 2p, 2p+1
#define BATCH 32

__device__ __forceinline__ float2 cmul(float2 a, float2 b) {
    return make_float2(fmaf(a.x, b.x, -(a.y * b.y)),
                       fmaf(a.x, b.y,  (a.y * b.x)));
}
__device__ __forceinline__ float2 cconj(float2 a) { return make_float2(a.x, -a.y); }

// Forward 4-point DFT: X[k] = sum_n v[n] * (-i)^(n*k)
__device__ __forceinline__ void dft4(float2 v[4]) {
    float2 a = make_float2(v[0].x + v[2].x, v[0].y + v[2].y);
    float2 b = make_float2(v[0].x - v[2].x, v[0].y - v[2].y);
    float2 c = make_float2(v[1].x + v[3].x, v[1].y + v[3].y);
    float2 d = make_float2(v[1].x - v[3].x, v[1].y - v[3].y);
    v[0] = make_float2(a.x + c.x, a.y + c.y);
    v[2] = make_float2(a.x - c.x, a.y - c.y);
    v[1] = make_float2(b.x + d.y, b.y - d.x);   // b - i*d
    v[3] = make_float2(b.x - d.y, b.y + d.x);   // b + i*d
}

// w[e] = exp(i * e * ang), e = 0..15 (ang negative for forward FFT).
// Built from 3 sincos with product depth <= 2 for accuracy.
__device__ __forceinline__ void twpows(float ang, float2 w[16]) {
    float s1, c1, s4, c4, s8, c8;
    __sincosf(ang, &s1, &c1);
    __sincosf(4.0f * ang, &s4, &c4);
    __sincosf(8.0f * ang, &s8, &c8);
    float2 w1 = make_float2(c1, s1);
    float2 w4 = make_float2(c4, s4);
    float2 w8 = make_float2(c8, s8);
    w[0]  = make_float2(1.0f, 0.0f);
    w[1]  = w1;
    w[2]  = cmul(w1, w1);
    w[3]  = cmul(w4, cconj(w1));
    w[4]  = w4;
    w[5]  = cmul(w4, w1);
    w[6]  = cmul(w8, cconj(w[2]));
    w[7]  = cmul(w8, cconj(w1));
    w[8]  = w8;
    w[9]  = cmul(w8, w1);
    w[10] = cmul(w8, w[2]);
    w[12] = cmul(w8, w4);
    w[11] = cmul(w[12], cconj(w1));
    w[13] = cmul(w[12], w1);
    w[14] = cmul(w[12], w[2]);
    w[15] = cmul(w[12], w[3]);
}

// o[k] = sum_n v[n] * exp(-2pi i n k / 16), natural order in and out.
// 16 = 4x4: inner dft4 over n_hi, twiddle W16^(n_lo*k_lo), outer dft4 over n_lo.
__device__ __forceinline__ void dft16(const float2 v[16], float2 o[16]) {
    const float C1 = 0.92387953251128675613f;   // cos(pi/8)
    const float S1 = 0.38268343236508977173f;   // sin(pi/8)
    const float R2 = 0.70710678118654752440f;   // sqrt(2)/2
    float2 c[4][4];                              // c[n1a][k1a]
#pragma unroll
    for (int a = 0; a < 4; ++a) {
        float2 t[4] = { v[a], v[a + 4], v[a + 8], v[a + 12] };
        dft4(t);
#pragma unroll
        for (int k = 0; k < 4; ++k) c[a][k] = t[k];
    }
    // c[n1a][k1a] *= W16^(n1a*k1a)
    c[1][1] = cmul(c[1][1], make_float2( C1, -S1));
    c[1][2] = cmul(c[1][2], make_float2( R2, -R2));
    c[1][3] = cmul(c[1][3], make_float2( S1, -C1));
    c[2][1] = cmul(c[2][1], make_float2( R2, -R2));
    c[2][2] = make_float2(c[2][2].y, -c[2][2].x);          // * W16^4 = -i
    c[2][3] = cmul(c[2][3], make_float2(-R2, -R2));
    c[3][1] = cmul(c[3][1], make_float2( S1, -C1));
    c[3][2] = cmul(c[3][2], make_float2(-R2, -R2));
    c[3][3] = cmul(c[3][3], make_float2(-C1,  S1));        // W16^9 = -W16^1
#pragma unroll
    for (int k1a = 0; k1a < 4; ++k1a) {
        float2 t[4] = { c[0][k1a], c[1][k1a], c[2][k1a], c[3][k1a] };
        dft4(t);
#pragma unroll
        for (int k1b = 0; k1b < 4; ++k1b) o[k1a + 4 * k1b] = t[k1b];
    }
}

// One 64-lane wave computes one window-pair via the two-for-one complex FFT:
//   s[n] = a[n] + i*b[n],  S = FFT1024(s),
//   Re A[k] = (S[k].x + S[-k].x)/2,  Re B[k] = (S[k].y + S[-k].y)/2.
// FFT1024 = radix-4 (regs, from float4 loads) x DFT16 (regs) x DFT16 (regs),
// with 2 XOR-swizzled LDS exchanges, ZERO __syncthreads (wave-synchronous,
// DS ops execute in issue order within a wave; exchange-2 writes data-depend
// on every exchange-1 read via dft16, so compiler ordering is guaranteed).
// n = n2 + 16*n1 + 256*n0, k = k0 + 4*k1 + 64*k2, lane' = k0 + 4*k1.
__global__ __launch_bounds__(256) void StridedFourier_kernel(
    const float* __restrict__ x, float* __restrict__ out)
{
    __shared__ __align__(16) float2 lds[4][NFFT];

    const int tid  = threadIdx.x;
    const int lane = tid & 63;
    const int wid  = tid >> 6;

    // XCD-aware swizzle: blocks with equal (blockIdx.x % 8) share an XCD under
    // round-robin dispatch; give each XCD 16 consecutive pair-blocks.
    int bx = blockIdx.x;                 // 0..127
    bx = ((bx & 7) << 4) | (bx >> 3);    // bijective on 128
    const int p = bx * 4 + wid;          // window pair
    if (p >= NPAIR) return;              // one idle wave in one block
    const int bat = blockIdx.y;
    const bool wbv = (2 * p + 1) < NWIN; // last pair is a singleton

    const float* src = x + (size_t)bat * TIME_ + (size_t)p * 512;
    float2* L = lds[wid];

    // ---- global load: 5 float4 per lane (20 samples), fully coalesced ----
    float Ls[20];
#pragma unroll
    for (int c = 0; c < 4; ++c) {
        float4 f = *(const float4*)(src + 4 * lane + 256 * c);
        Ls[4 * c + 0] = f.x; Ls[4 * c + 1] = f.y;
        Ls[4 * c + 2] = f.z; Ls[4 * c + 3] = f.w;
    }
    if (wbv) {
        float4 f = *(const float4*)(src + 4 * lane + 1024);
        Ls[16] = f.x; Ls[17] = f.y; Ls[18] = f.z; Ls[19] = f.w;
    } else {
        Ls[16] = Ls[17] = Ls[18] = Ls[19] = 0.0f;  // OOB guard, b-window unused
    }

    // ---- stage 1: radix-4 over n0 (stride 256), write A[n2][k0][n1] ----
    // idx = 4*lane + t = n2 + 16*n1; LDS slot = 64*n2 + 16*k0 + (n1 ^ 2*(n2&7))
#pragma unroll
    for (int t = 0; t < 4; ++t) {
        float2 v[4];
#pragma unroll
        for (int n0 = 0; n0 < 4; ++n0)
            v[n0] = make_float2(Ls[4 * n0 + t], Ls[4 * n0 + 4 + t]);
        dft4(v);
        const int idx = 4 * lane + t;
        const int n2 = idx & 15, n1 = idx >> 4;
        const int wb = 64 * n2 + (n1 ^ ((n2 & 7) << 1));
#pragma unroll
        for (int k0 = 0; k0 < 4; ++k0)
            L[wb + 16 * k0] = v[k0];
    }

    // ---- exchange 1 read: lane owns (n2 = lane&15, k0 = lane>>4) ----
    const int n2r = lane & 15, k0r = lane >> 4;
    float2 Av[16];
    {
        const int rb = 64 * n2r + 16 * k0r;
        const int m  = (n2r & 7) << 1;
#pragma unroll
        for (int u = 0; u < 8; ++u) {
            float4 q = *(const float4*)&L[rb + ((2 * u) ^ m)];
            Av[2 * u]     = make_float2(q.x, q.y);
            Av[2 * u + 1] = make_float2(q.z, q.w);
        }
    }

    // ---- stage 2: twiddle W64^(n1*k0), DFT16 over n1 -> k1 ----
    float2 w[16];
    twpows(-0.0981747704246810387f * (float)k0r, w);   // -2pi/64 * k0
#pragma unroll
    for (int i = 1; i < 16; ++i) Av[i] = cmul(Av[i], w[i]);
    float2 Bv[16];
    dft16(Av, Bv);

    // ---- exchange 2 write: B[n2][k0][k1] -> slot 16*(k0+4k1) + (n2 ^ swz) ----
#pragma unroll
    for (int k1 = 0; k1 < 16; ++k1) {
        const int lp = k0r + 4 * k1;
        L[16 * lp + (n2r ^ ((lp & 7) << 1))] = Bv[k1];
    }

    // ---- exchange 2 read: lane' = k0 + 4*k1 = lane, 16 consecutive n2 ----
    float2 Cv[16];
    {
        const int rb2 = 16 * lane;
        const int m2  = (lane & 7) << 1;
#pragma unroll
        for (int u = 0; u < 8; ++u) {
            float4 q = *(const float4*)&L[rb2 + ((2 * u) ^ m2)];
            Cv[2 * u]     = make_float2(q.x, q.y);
            Cv[2 * u + 1] = make_float2(q.z, q.w);
        }
    }

    // ---- stage 3: twiddle W1024^(n2*lane'), DFT16 over n2 -> k2 ----
    twpows(-0.00613592315154256491f * (float)lane, w); // -2pi/1024 * lane'
#pragma unroll
    for (int i = 1; i < 16; ++i) Cv[i] = cmul(Cv[i], w[i]);
    float2 Sv[16];                                     // Sv[k2] = S[lane + 64*k2]
    dft16(Cv, Sv);

    // ---- untangle via single-partner shuffle + coalesced stores ----
    // mirror of k = lane + 64*k2 lives in lane (64-lane)&63 at element 15-k2
    // (lane 0: self, element (16-k2)&15).
    const long long cbase = ((long long)bat * NWIN + 2LL * p) * NFFT;
    float* oa = out + cbase + lane;
    float* ob = oa + NFFT;
    const int prt = (64 - lane) & 63;
#pragma unroll
    for (int k2 = 0; k2 < 16; ++k2) {
        float mx = __shfl(Sv[15 - k2].x, prt, 64);
        float my = __shfl(Sv[15 - k2].y, prt, 64);
        if (lane == 0) {
            mx = Sv[(16 - k2) & 15].x;
            my = Sv[(16 - k2) & 15].y;
        }
        oa[64 * k2] = 0.5f * (Sv[k2].x + mx);
        if (wbv) ob[64 * k2] = 0.5f * (Sv[k2].y + my);
    }
}

extern "C" void kernel_launch(void* const* d_in, const int* in_sizes, int n_in,
                              void* d_out, int out_size, void* d_ws, size_t ws_size,
                              hipStream_t stream) {
    const float* x = (const float*)d_in[0];
    float* out = (float*)d_out;
    dim3 grid(128, BATCH);               // 128 blocks * 4 waves = 512 >= 511 pairs
    StridedFourier_kernel<<<grid, 256, 0, stream>>>(x, out);
}